// Round 20
// baseline (51.432 us; speedup 1.0000x reference)
//
#include <hip/hip_runtime.h>
#include <math.h>

#define Bb 4
#define Nn 4096
#define Hh 128
#define Ff 64
#define CAP 128  // max neighbors kept per row (deg ~41 +/- 6.4; 13 sigma)

typedef __attribute__((ext_vector_type(8))) short bf16x8;
typedef __attribute__((ext_vector_type(4))) float f32x4;

// bf16 helpers (RNE)
__device__ __forceinline__ unsigned short f2bf(float f) {
  unsigned int u = __float_as_uint(f);
  u += 0x7fffu + ((u >> 16) & 1u);
  return (unsigned short)(u >> 16);
}
__device__ __forceinline__ float bf2f(unsigned short h) {
  return __uint_as_float(((unsigned int)h) << 16);
}

// ---------------------------------------------------------------------------
// prep2_kernel (R16 verbatim): 3072 blocks.
//   bid <  1024 : QKV, 16 rows, bf16 MFMA (R12-verified body).
//   bid >= 1024 : pure bitmask stream: float4 load -> 4 ballots -> 4 u64.
// ---------------------------------------------------------------------------
__global__ __launch_bounds__(256) void prep2_kernel(
    const float* __restrict__ x,
    const float* __restrict__ Wq,
    const float* __restrict__ Wk,
    const float* __restrict__ Wv,
    const float* __restrict__ adj,
    float* __restrict__ q,
    unsigned short* __restrict__ kb,
    unsigned short* __restrict__ vb,
    unsigned long long* __restrict__ bm) {
  __shared__ short xs[16 * 128];  // 4KB bf16, swizzled (QKV role only)

  const int tid = threadIdx.x;
  const int w = tid >> 6;
  const int lane = tid & 63;
  const int bid = (int)blockIdx.x;

  if (bid < 1024) {
    const int row0 = bid * 16;
    const int half = lane >> 4;  // 0..3
    const int l16 = lane & 15;

    const float4* xg = (const float4*)(x + (size_t)row0 * Hh);
#pragma unroll
    for (int j = 0; j < 2; ++j) {
      const int idx = tid + 256 * j;  // float4 index; 32 per row
      const int row = idx >> 5;
      const int c4 = idx & 31;
      const float4 xv = xg[idx];
      uint2 p;
      p.x = (unsigned)f2bf(xv.x) | ((unsigned)f2bf(xv.y) << 16);
      p.y = (unsigned)f2bf(xv.z) | ((unsigned)f2bf(xv.w) << 16);
      const int addr = (row * 256 + c4 * 8) ^ ((row & 7) << 4);
      *(uint2*)((char*)xs + addr) = p;
    }

    bf16x8 bfr[3][4];
#pragma unroll
    for (int nt = 0; nt < 3; ++nt) {
      const int n0g = w * 48 + nt * 16;
      const float* Wm = (n0g < 64) ? Wq : (n0g < 128) ? Wk : Wv;
      const int c0 = n0g & 63;
#pragma unroll
      for (int ks = 0; ks < 4; ++ks) {
        bf16x8 f;
#pragma unroll
        for (int j = 0; j < 8; ++j) {
          const int kr = ks * 32 + half * 8 + j;
          f[j] = (short)f2bf(Wm[kr * Ff + c0 + l16]);
        }
        bfr[nt][ks] = f;
      }
    }
    __syncthreads();

    f32x4 acc[3];
#pragma unroll
    for (int nt = 0; nt < 3; ++nt)
#pragma unroll
      for (int r = 0; r < 4; ++r) acc[nt][r] = 0.f;

#pragma unroll
    for (int ks = 0; ks < 4; ++ks) {
      const int addr = (l16 * 256 + ks * 64 + half * 16) ^ ((l16 & 7) << 4);
      const bf16x8 a = *(const bf16x8*)((const char*)xs + addr);
#pragma unroll
      for (int nt = 0; nt < 3; ++nt) {
        acc[nt] = __builtin_amdgcn_mfma_f32_16x16x32_bf16(a, bfr[nt][ks],
                                                          acc[nt], 0, 0, 0);
      }
    }

#pragma unroll
    for (int nt = 0; nt < 3; ++nt) {
      const int n0g = w * 48 + nt * 16;
      const int col = (n0g & 63) + l16;
#pragma unroll
      for (int r = 0; r < 4; ++r) {
        const size_t rowg = (size_t)row0 + half * 4 + r;
        const float val = acc[nt][r];
        if (n0g < 64)
          q[rowg * Ff + col] = val;
        else if (n0g < 128)
          kb[rowg * Ff + col] = f2bf(val);
        else
          vb[rowg * Ff + col] = f2bf(val);
      }
    }
  } else {
    const int sid = bid - 1024;                // [0, 2048)
    const int wg = sid * 4 + w;                // wave id [0, 8192)
    const float4* base = ((const float4*)adj) + ((size_t)wg * 8) * 64 + lane;

    float4 a[8];
#pragma unroll
    for (int it = 0; it < 8; ++it) a[it] = base[it * 64];

#pragma unroll
    for (int it = 0; it < 8; ++it) {
      const unsigned long long b0 = __ballot(a[it].x != 0.f);
      const unsigned long long b1 = __ballot(a[it].y != 0.f);
      const unsigned long long b2 = __ballot(a[it].z != 0.f);
      const unsigned long long b3 = __ballot(a[it].w != 0.f);
      const unsigned long long bsel =
          lane == 0 ? b0 : lane == 1 ? b1 : lane == 2 ? b2 : b3;
      if (lane < 4) bm[((size_t)wg * 8 + it) * 4 + lane] = bsel;
    }
  }
}

// ---------------------------------------------------------------------------
// attn_kernel: R16 body, ONE structural change — 1024-thread blocks covering
// 4 rows each (grid 4096->1024). R18 counters showed Occupancy 45% /
// VALUBusy 31% with only 40 VGPR + 3.5KB LDS: the cap isn't a resource,
// it's the many-tiny-workgroups dispatch limit (~14 of 32 waves resident).
// 16-wave blocks let 2 blocks/CU fill all 32 wave slots.
//   wave w: row r = w>>2 (n = 4*blockIdx.x + r), batch b = w&3.
//   expand: waves 0..3 in PARALLEL (wave w expands bm row n0+w).
//   score/PV: R16 verbatim (scalar LDS broadcasts — R18's b128 batching
//   and R19's reg-prefetch both regressed).
// ---------------------------------------------------------------------------
__global__ __launch_bounds__(1024) void attn_kernel(
    const unsigned long long* __restrict__ bm,
    const float* __restrict__ q,
    const unsigned short* __restrict__ kb,
    const unsigned short* __restrict__ vb,
    float* __restrict__ out) {
  __shared__ __align__(8) unsigned short nbr[4][CAP];
  __shared__ float qs[4][4][64];   // [row r][batch b][feature]
  __shared__ float ps[16][64];     // per wave
  __shared__ int s_tot[4];

  const int n0 = (int)blockIdx.x * 4;
  const int tid = threadIdx.x;
  const int w = tid >> 6;    // 0..15
  const int lane = tid & 63;
  const int r = w >> 2;      // row within block
  const int b = w & 3;       // batch
  const int n = n0 + r;

  // each wave stages q for its (b, n) pair
  qs[r][b][lane] = q[((size_t)b * Nn + n) * Ff + lane];

  // expand: waves 0..3 each expand one bitmask row (parallel)
  if (w < 4) {
    const int ne = n0 + w;
    ((ushort2*)nbr[w])[lane] = make_ushort2(0, 0);  // zero-pad
    unsigned long long m = bm[(size_t)ne * 64 + lane];  // coalesced 512B
    const int cnt = __popcll(m);
    int inc = cnt;
#pragma unroll
    for (int o = 1; o < 64; o <<= 1) {
      const int t = __shfl_up(inc, o, 64);
      if (lane >= o) inc += t;
    }
    int pos = inc - cnt;  // exclusive offset
    const int colbase = ((lane >> 2) << 8) + (lane & 3);
    while (m) {
      const int i = __builtin_ctzll(m);
      if (pos < CAP) nbr[w][pos] = (unsigned short)(colbase + (i << 2));
      ++pos;
      m &= m - 1;
    }
    if (lane == 63) s_tot[w] = inc;
  }
  __syncthreads();

  const int tot = s_tot[r] < CAP ? s_tot[r] : CAP;
  const unsigned short* nbrr = nbr[r];

  const unsigned short* kbb = kb + (size_t)b * Nn * Ff;
  const unsigned short* vbb = vb + (size_t)b * Nn * Ff;

  const int g = lane >> 2;  // row group 0..15
  const int sl = lane & 3;  // sub-lane

  float4 q0a = *(const float4*)&qs[r][b][8 * sl];
  float4 q0b = *(const float4*)&qs[r][b][8 * sl + 4];
  float4 q1a = *(const float4*)&qs[r][b][32 + 8 * sl];
  float4 q1b = *(const float4*)&qs[r][b][32 + 8 * sl + 4];

  float M = -INFINITY, L = 0.f, acc = 0.f, vsum = 0.f;

  const int ntiles = (tot + 63) >> 6;
  for (int t = 0; t < ntiles; ++t) {
    const int tbase = t << 6;

    float s0, s1, s2, s3;
#define BPAIR(u, qlo, qhi, a)                                   \
    {                                                           \
      const float flo = __uint_as_float((u) << 16);             \
      const float fhi = __uint_as_float((u) & 0xffff0000u);     \
      a = fmaf(qlo, flo, a);                                    \
      a = fmaf(qhi, fhi, a);                                    \
    }
#define DOT_ROW(i, sdst)                                                  \
    {                                                                     \
      const int idx = tbase + g + 16 * (i);                               \
      const bool valid = idx < tot;                                       \
      const int m = valid ? (int)nbrr[idx] : 0;                           \
      const char* krow = (const char*)(kbb + (size_t)m * Ff);             \
      const uint4 k0 = *(const uint4*)(krow + 16 * sl);                   \
      const uint4 k1 = *(const uint4*)(krow + 64 + 16 * sl);              \
      float a = 0.f;                                                      \
      BPAIR(k0.x, q0a.x, q0a.y, a)                                        \
      BPAIR(k0.y, q0a.z, q0a.w, a)                                        \
      BPAIR(k0.z, q0b.x, q0b.y, a)                                        \
      BPAIR(k0.w, q0b.z, q0b.w, a)                                        \
      BPAIR(k1.x, q1a.x, q1a.y, a)                                        \
      BPAIR(k1.y, q1a.z, q1a.w, a)                                        \
      BPAIR(k1.z, q1b.x, q1b.y, a)                                        \
      BPAIR(k1.w, q1b.z, q1b.w, a)                                        \
      a += __shfl_xor(a, 1, 64);                                          \
      a += __shfl_xor(a, 2, 64);                                          \
      sdst = valid ? a * 0.125f : -INFINITY;                              \
    }
    DOT_ROW(0, s0)
    DOT_ROW(1, s1)
    DOT_ROW(2, s2)
    DOT_ROW(3, s3)
#undef DOT_ROW
#undef BPAIR

    // max-reduce: groups only (within-group identical after shfl 1,2)
    float lm = fmaxf(fmaxf(s0, s1), fmaxf(s2, s3));
#pragma unroll
    for (int o = 32; o >= 4; o >>= 1) lm = fmaxf(lm, __shfl_xor(lm, o, 64));
    const float newM = fmaxf(M, lm);

    const float p0 = (s0 == -INFINITY) ? 0.f : __expf(s0 - newM);
    const float p1 = (s1 == -INFINITY) ? 0.f : __expf(s1 - newM);
    const float p2 = (s2 == -INFINITY) ? 0.f : __expf(s2 - newM);
    const float p3 = (s3 == -INFINITY) ? 0.f : __expf(s3 - newM);

    // psum: groups only (R3-bug guard: offsets 2,1 would 4x-count)
    float psum = ((p0 + p1) + (p2 + p3));
#pragma unroll
    for (int o = 32; o >= 4; o >>= 1) psum += __shfl_xor(psum, o, 64);

    const float corr = __expf(M - newM);  // t==0: exp(-inf)=0, L=acc=0
    L = L * corr + psum;
    acc *= corr;
    M = newM;

    const float pw = sl == 0 ? p0 : sl == 1 ? p1 : sl == 2 ? p2 : p3;
    ps[w][g + 16 * sl] = pw;

    const int jmax = min(64, tot - tbase);
#pragma unroll 4
    for (int j = 0; j < jmax; ++j) {
      const int m = nbrr[tbase + j];                      // LDS broadcast
      const float vf = bf2f(vbb[(size_t)m * Ff + lane]);  // coalesced 128B
      acc = fmaf(ps[w][j], vf, acc);                      // p broadcast
      vsum += vf;
    }
  }

  out[((size_t)b * Nn + n) * Ff + lane] = acc / L + vsum;
}

// ---------------------------------------------------------------------------
extern "C" void kernel_launch(void* const* d_in, const int* in_sizes, int n_in,
                              void* d_out, int out_size, void* d_ws, size_t ws_size,
                              hipStream_t stream) {
  const float* x = (const float*)d_in[0];
  const float* Wq = (const float*)d_in[1];
  const float* Wk = (const float*)d_in[2];
  const float* Wv = (const float*)d_in[3];
  const float* adj = (const float*)d_in[4];
  float* out = (float*)d_out;

  char* ws = (char*)d_ws;
  const size_t rows = (size_t)Bb * Nn;  // 16384
  float* q = (float*)ws;                                       // 4 MiB
  unsigned short* kb = (unsigned short*)(ws + rows * Ff * 4);  // 2 MiB
  unsigned short* vb = (unsigned short*)(ws + rows * Ff * 4 + rows * Ff * 2);
  unsigned long long* bm = (unsigned long long*)(ws + rows * Ff * 8);  // 2 MiB

  prep2_kernel<<<dim3(3072), dim3(256), 0, stream>>>(
      x, Wq, Wk, Wv, adj, q, kb, vb, bm);
  attn_kernel<<<dim3(Nn / 4), dim3(1024), 0, stream>>>(bm, q, kb, vb, out);
}